// Round 6
// baseline (282.529 us; speedup 1.0000x reference)
//
#include <hip/hip_runtime.h>
#include <stdint.h>

#define N_IT 10000
#define NPAD 10048          // 157*64
#define DH 128
#define C2 256
#define C3 384
#define BATCH 1024
#define HIST 100
#define NS 50               // k-splits for G partials (200 rows each)
#define NTRI 10             // upper-triangle 64x64 tiles of G

typedef __attribute__((ext_vector_type(2))) float f32x2;
typedef __attribute__((ext_vector_type(4))) float f32x4;
typedef __attribute__((ext_vector_type(8))) short s16x8;
typedef unsigned int uint32;

__device__ __forceinline__ unsigned short f2b(float x){
    union { float f; uint32_t u; } v; v.f = x;
    uint32_t r = (v.u + 0x7FFF + ((v.u >> 16) & 1)) >> 16;
    return (unsigned short)r;
}
__device__ __forceinline__ float b2f(unsigned short u){
    union { uint32_t u; float f; } v; v.u = ((uint32_t)u) << 16;
    return v.f;
}

// ---------------- prep: bf16 copies, 8 elems/thread ----------------
__global__ void prep_kernel(const float* __restrict__ emb_in, const float* __restrict__ emb_out,
                            const float* __restrict__ emb_item,
                            const float* __restrict__ Wq, const float* __restrict__ Wk,
                            const float* __restrict__ Wv,
                            unsigned short* __restrict__ Qbf,
                            unsigned short* __restrict__ WqB, unsigned short* __restrict__ WkB,
                            unsigned short* __restrict__ WvTB, unsigned short* __restrict__ Hsrc)
{
    int idx = blockIdx.x * 256 + threadIdx.x;
    const int nQ8 = NPAD*C2/8;      // 321536
    const int nW8 = C3*C3/8;        // 18432
    const int nH8 = N_IT*DH/8;      // 160000
    if (idx < nQ8) {
        int i = idx >> 5, c8 = (idx & 31) * 8;
        int sr = min(i, N_IT-1);
        const float* src = (c8 < DH) ? (emb_in + (size_t)sr*DH + c8)
                                     : (emb_out + (size_t)sr*DH + (c8-DH));
        f32x4 a = *(const f32x4*)src, b = *(const f32x4*)(src+4);
        s16x8 o;
        #pragma unroll
        for (int k = 0; k < 4; k++) { o[k] = (short)f2b(a[k]); o[4+k] = (short)f2b(b[k]); }
        *(s16x8*)(Qbf + (size_t)idx*8) = o;
    } else if (idx < nQ8 + 2*nW8) {
        int t = idx - nQ8;
        int m = t / nW8, r8 = (t % nW8) * 8;
        const float* src = (m == 0) ? (Wq + r8) : (Wk + r8);
        unsigned short* dst = (m == 0) ? WqB : WkB;
        f32x4 a = *(const f32x4*)src, b = *(const f32x4*)(src+4);
        s16x8 o;
        #pragma unroll
        for (int k = 0; k < 4; k++) { o[k] = (short)f2b(a[k]); o[4+k] = (short)f2b(b[k]); }
        *(s16x8*)(dst + r8) = o;
    } else if (idx < nQ8 + 3*nW8) {
        int t = (idx - nQ8 - 2*nW8) * 8;    // flat index into WvTB
        int e = t / C3, d0 = t % C3;
        s16x8 o;
        #pragma unroll
        for (int k = 0; k < 8; k++) o[k] = (short)f2b(Wv[(size_t)(d0+k)*C3 + e]);
        *(s16x8*)(WvTB + t) = o;
    } else if (idx < nQ8 + 3*nW8 + nH8) {
        int t = idx - nQ8 - 3*nW8;
        int i = t >> 4, c8 = (t & 15) * 8;
        const float* src = emb_item + (size_t)i*DH + c8;
        f32x4 a = *(const f32x4*)src, b = *(const f32x4*)(src+4);
        s16x8 o;
        #pragma unroll
        for (int k = 0; k < 4; k++) { o[k] = (short)f2b(a[k]); o[4+k] = (short)f2b(b[k]); }
        *(s16x8*)(Hsrc + (size_t)i*C3 + c8) = o;
    }
}

// ---------------- G partials: G = Q^T Q (f32), 10 tri-tiles x 50 k-splits ----------------
__global__ void gpart_kernel(const float* __restrict__ emb_in, const float* __restrict__ emb_out,
                             float* __restrict__ Gpart, float* __restrict__ qsp)
{
    __shared__ float QA[8][64], QB[8][64];
    int bid = blockIdx.x;
    int split = bid % NS;
    int tile  = bid / NS;          // 0..9 upper triangle
    int ta = (tile < 4) ? 0 : (tile < 7) ? 1 : (tile < 9) ? 2 : 3;
    const int base_[4] = {0, 4, 7, 9};
    int tb = tile - base_[ta] + ta;
    int tid = threadIdx.x;
    int ty = tid >> 4, tx = tid & 15;

    const float* srcA = (ta < 2) ? (emb_in + ta*64) : (emb_out + (ta-2)*64);
    const float* srcB = (tb < 2) ? (emb_in + tb*64) : (emb_out + (tb-2)*64);

    float g[4][4];
    #pragma unroll
    for (int r = 0; r < 4; r++)
        #pragma unroll
        for (int c = 0; c < 4; c++) g[r][c] = 0.f;
    float qs = 0.f;

    int r0 = split * 200;
    int rr = tid >> 5, c2 = (tid & 31) * 2;
    for (int ch = 0; ch < 25; ch++) {
        int rows = r0 + ch*8;
        *(f32x2*)&QA[rr][c2] = *(const f32x2*)&srcA[(size_t)(rows+rr)*DH + c2];
        *(f32x2*)&QB[rr][c2] = *(const f32x2*)&srcB[(size_t)(rows+rr)*DH + c2];
        __syncthreads();
        #pragma unroll
        for (int k = 0; k < 8; k++) {
            f32x4 a = *(const f32x4*)&QA[k][ty*4];
            f32x4 b = *(const f32x4*)&QB[k][tx*4];
            #pragma unroll
            for (int r = 0; r < 4; r++)
                #pragma unroll
                for (int c = 0; c < 4; c++) g[r][c] += a[r]*b[c];
        }
        if (ta == tb && tid < 64) {
            #pragma unroll
            for (int k = 0; k < 8; k++) qs += QA[k][tid];
        }
        __syncthreads();
    }

    float* gout = Gpart + ((size_t)(split*NTRI + tile) << 12);
    #pragma unroll
    for (int r = 0; r < 4; r++)
        #pragma unroll
        for (int c = 0; c < 4; c++)
            gout[(ty*4 + r)*64 + tx*4 + c] = g[r][c];
    if (ta == tb && tid < 64) qsp[split*C2 + ta*64 + tid] = qs;
}

// ---------------- combine G partials -> GTswB bf16 [e][d] = G[d^128][e]; qsumF ----------------
__global__ void gcomb_kernel(const float* __restrict__ Gpart, const float* __restrict__ qsp,
                             unsigned short* __restrict__ GTswB, float* __restrict__ qsumF)
{
    int bid = blockIdx.x, tid = threadIdx.x;
    if (bid < 256) {
        int d = bid, e = tid;
        int ta = d >> 6, dl = d & 63, tb = e >> 6, el = e & 63;
        const int base_[4] = {0, 4, 7, 9};
        int tile, ro, co;
        if (ta <= tb) { tile = base_[ta] + (tb - ta); ro = dl; co = el; }
        else          { tile = base_[tb] + (ta - tb); ro = el; co = dl; }
        float s = 0.f;
        for (int sp = 0; sp < NS; sp++)
            s += Gpart[((size_t)(sp*NTRI + tile) << 12) + ro*64 + co];
        GTswB[e*C2 + (d ^ 128)] = f2b(s);
    } else {
        float s = 0.f;
        for (int sp = 0; sp < NS; sp++) s += qsp[sp*C2 + tid];
        qsumF[tid] = s;
    }
}

// ---------------- region GEMM (+fused D) -> Hsrc[:,128:384] bf16 ----------------
__global__ __launch_bounds__(256, 2) void gemmy_kernel(
    const unsigned short* __restrict__ Qbf, const unsigned short* __restrict__ GTswB,
    const float* __restrict__ qsumF, unsigned short* __restrict__ Hsrc)
{
    __shared__ __align__(16) unsigned short As[64*C2];  // 32KB swizzled
    __shared__ float ksumL[C2];
    __shared__ float Dl[64];
    int tid = threadIdx.x;
    int bm = blockIdx.x;

    #pragma unroll
    for (int p = 0; p < 8; p++) {
        int ch = tid + p*256;
        int r = ch >> 5, ci = ch & 31;
        s16x8 v = *(const s16x8*)(Qbf + (size_t)(bm*64 + r)*C2 + ci*8);
        *(s16x8*)((char*)As + r*512 + ((ci*16) ^ ((r&7)<<4))) = v;
    }
    ksumL[tid] = qsumF[tid ^ 128];
    __syncthreads();

    int w = tid >> 6, l = tid & 63, lm = l & 15, lq = l >> 4;

    // fused D phase: D[r] = N + (q_r . ksum)/16
    {
        float k0 = ksumL[l*4], k1 = ksumL[l*4+1], k2 = ksumL[l*4+2], k3 = ksumL[l*4+3];
        for (int i = 0; i < 16; i++) {
            int r = w*16 + i;
            const char* p = (const char*)As + r*512 + ((((l>>1)*16) ^ ((r&7)<<4)) + (l&1)*8);
            uint32 u0 = *(const uint32*)p, u1 = *(const uint32*)(p+4);
            float acc = b2f(u0 & 0xffff)*k0 + b2f(u0 >> 16)*k1
                      + b2f(u1 & 0xffff)*k2 + b2f(u1 >> 16)*k3;
            #pragma unroll
            for (int d = 1; d < 64; d <<= 1) acc += __shfl_xor(acc, d);
            if (l == 0) Dl[r] = (float)N_IT + acc * 0.0625f;
        }
    }
    __syncthreads();

    f32x4 acc[4][4];
    #pragma unroll
    for (int j = 0; j < 4; j++)
        #pragma unroll
        for (int m = 0; m < 4; m++) acc[j][m] = (f32x4){0,0,0,0};

    for (int kk = 0; kk < 8; kk++) {
        s16x8 a[4];
        #pragma unroll
        for (int m = 0; m < 4; m++) {
            int r = m*16 + lm;
            a[m] = *(const s16x8*)((char*)As + r*512 + ((64*kk + 16*lq) ^ ((r&7)<<4)));
        }
        #pragma unroll
        for (int j = 0; j < 4; j++) {
            int n = w*64 + j*16 + lm;
            s16x8 bf = *(const s16x8*)(GTswB + (size_t)n*C2 + kk*32 + lq*8);
            #pragma unroll
            for (int m = 0; m < 4; m++)
                acc[j][m] = __builtin_amdgcn_mfma_f32_16x16x32_bf16(a[m], bf, acc[j][m], 0,0,0);
        }
    }
    #pragma unroll
    for (int j = 0; j < 4; j++) {
        int col = w*64 + j*16 + lm;
        float qv = qsumF[col];
        #pragma unroll
        for (int m = 0; m < 4; m++)
            #pragma unroll
            for (int r = 0; r < 4; r++) {
                int row = bm*64 + m*16 + lq*4 + r;
                if (row < N_IT) {
                    float v = (qv + acc[j][m][r] * 0.0625f) / Dl[m*16 + lq*4 + r];
                    Hsrc[(size_t)row*C3 + DH + col] = f2b(v);
                }
            }
    }
}

// ---------------- per-item fused: cvI + KE=H@Wk^T+bk (bf16); QI=H@Wq^T+bq; GI=H@Wv ----------------
__global__ __launch_bounds__(256, 2) void item_kernel(
    const unsigned short* __restrict__ Hsrc,
    const unsigned short* __restrict__ WkB, const unsigned short* __restrict__ WqB,
    const unsigned short* __restrict__ WvTB,
    const float* __restrict__ bk, const float* __restrict__ bq, const float* __restrict__ bv,
    unsigned short* __restrict__ KE, float* __restrict__ QI, float* __restrict__ GI,
    float* __restrict__ cvI)
{
    __shared__ __align__(16) unsigned short As[64*C3];  // 48KB swizzled
    int tid = threadIdx.x;
    int bm = blockIdx.x;

    for (int ch = tid; ch < 64*48; ch += 256) {
        int r = ch / 48, ci = ch % 48;
        int row = min(bm*64 + r, N_IT-1);
        s16x8 v = *(const s16x8*)(Hsrc + (size_t)row*C3 + ci*8);
        *(s16x8*)((char*)As + r*768 + ((ci*16) ^ ((r&7)<<4))) = v;
    }
    __syncthreads();

    int w = tid >> 6, l = tid & 63, lm = l & 15, lq = l >> 4;

    // cvI phase: direct global reads of Hsrc rows
    {
        float bvv[6];
        #pragma unroll
        for (int k = 0; k < 6; k++) bvv[k] = bv[l*6 + k];
        for (int i = 0; i < 16; i++) {
            int row0 = bm*64 + w*16 + i;
            int row = min(row0, N_IT-1);
            const uint32* hp = (const uint32*)(Hsrc + (size_t)row*C3) + l*3;
            uint32 a = hp[0], b_ = hp[1], c = hp[2];
            float p = b2f(a & 0xffff)*bvv[0] + b2f(a >> 16)*bvv[1]
                    + b2f(b_ & 0xffff)*bvv[2] + b2f(b_ >> 16)*bvv[3]
                    + b2f(c & 0xffff)*bvv[4] + b2f(c >> 16)*bvv[5];
            #pragma unroll
            for (int d = 1; d < 64; d <<= 1) p += __shfl_xor(p, d);
            if (l == 0 && row0 < N_IT) cvI[row0] = p;
        }
    }

    #pragma unroll 1
    for (int mm = 0; mm < 3; mm++) {
        const unsigned short* Bm = (mm == 0) ? WkB : (mm == 1) ? WqB : WvTB;
        f32x4 acc[6][4];
        #pragma unroll
        for (int j = 0; j < 6; j++)
            #pragma unroll
            for (int m = 0; m < 4; m++) acc[j][m] = (f32x4){0,0,0,0};

        for (int kk = 0; kk < 12; kk++) {
            s16x8 a[4];
            #pragma unroll
            for (int m = 0; m < 4; m++) {
                int r = m*16 + lm;
                a[m] = *(const s16x8*)((char*)As + r*768 + ((64*kk + 16*lq) ^ ((r&7)<<4)));
            }
            #pragma unroll
            for (int j = 0; j < 6; j++) {
                int n = (w*6 + j)*16 + lm;
                s16x8 bf = *(const s16x8*)(Bm + (size_t)n*C3 + kk*32 + lq*8);
                #pragma unroll
                for (int m = 0; m < 4; m++)
                    acc[j][m] = __builtin_amdgcn_mfma_f32_16x16x32_bf16(a[m], bf, acc[j][m], 0,0,0);
            }
        }
        #pragma unroll
        for (int j = 0; j < 6; j++) {
            int col = (w*6 + j)*16 + lm;
            float bias = (mm == 0) ? bk[col] : (mm == 1) ? bq[col] : 0.f;
            #pragma unroll
            for (int m = 0; m < 4; m++)
                #pragma unroll
                for (int r = 0; r < 4; r++) {
                    int row = bm*64 + m*16 + lq*4 + r;
                    if (row < N_IT) {
                        float v = acc[j][m][r] + bias;
                        if (mm == 0)      KE[(size_t)row*C3 + col] = f2b(v);
                        else if (mm == 1) QI[(size_t)row*C3 + col] = v;
                        else              GI[(size_t)row*C3 + col] = v;
                    }
                }
        }
    }
}

// ---------------- per-batch: row-once gather, quirk-binned scores, tiny LDS ----------------
__global__ __launch_bounds__(256, 2) void batchC_kernel(
    const int* __restrict__ user, const int* __restrict__ item_i, const int* __restrict__ item_j,
    const unsigned short* __restrict__ KE, const float* __restrict__ QI,
    const float* __restrict__ GI, const float* __restrict__ cvI,
    const unsigned short* __restrict__ Hsrc, float* __restrict__ out)
{
    __shared__ unsigned short rowK[8][C3];     // per-wave double-buffered K row (6 KB)
    __shared__ float qpA[C3], qpB[C3];         // 3 KB
    __shared__ int userL[HIST];
    __shared__ float dotP[HIST], dotN[HIST];
    __shared__ float sred[4][2][HIST];         // 3.2 KB

    int b = blockIdx.x, tid = threadIdx.x;
    int w = tid >> 6, lane = tid & 63;
    int ii = item_i[b], jj = item_j[b];

    if (tid < HIST) userL[tid] = user[b*HIST + tid];
    qpA[tid] = QI[(size_t)ii*C3 + tid];
    qpB[tid] = QI[(size_t)jj*C3 + tid];
    if (tid < 128) {
        qpA[256 + tid] = QI[(size_t)ii*C3 + 256 + tid];
        qpB[256 + tid] = QI[(size_t)jj*C3 + 256 + tid];
    }
    float gvp[6], gvn[6];
    #pragma unroll
    for (int k = 0; k < 6; k++) {
        gvp[k] = GI[(size_t)ii*C3 + lane*6 + k];
        gvn[k] = GI[(size_t)jj*C3 + lane*6 + k];
    }
    float cvii = cvI[ii], cvjj = cvI[jj];
    __syncthreads();

    // prologue: stage row 0 of this wave
    uint32 hc0, hc1, hc2;
    {
        int u = userL[w*25];
        const uint32* kp = (const uint32*)(KE + (size_t)u*C3) + lane*3;
        const uint32* hp = (const uint32*)(Hsrc + (size_t)u*C3) + lane*3;
        uint32 k0 = kp[0], k1 = kp[1], k2 = kp[2];
        hc0 = hp[0]; hc1 = hp[1]; hc2 = hp[2];
        uint32* kb = (uint32*)rowK[w*2];
        kb[lane*3] = k0; kb[lane*3+1] = k1; kb[lane*3+2] = k2;
    }

    float sA0 = 0.f, sA1 = 0.f, sB0 = 0.f, sB1 = 0.f;
    const float inv_s3 = 0.05103103630798287f;  // 1/sqrt(384)

    for (int r = 0; r < 25; r++) {
        int lr = w*25 + r;
        int buf = r & 1;

        // prefetch next row into registers (latency hides under compute)
        uint32 kn0=0, kn1=0, kn2=0, hn0=0, hn1=0, hn2=0;
        if (r < 24) {
            int u = userL[lr + 1];
            const uint32* kp = (const uint32*)(KE + (size_t)u*C3) + lane*3;
            const uint32* hp = (const uint32*)(Hsrc + (size_t)u*C3) + lane*3;
            kn0 = kp[0]; kn1 = kp[1]; kn2 = kp[2];
            hn0 = hp[0]; hn1 = hp[1]; hn2 = hp[2];
        }

        // scores: quirk bins. flat = lr*384 + d''; bin = flat%100; q idx = flat/100
        if (lane < 50) {
            const unsigned short* kr = rowK[w*2 + buf];
            int base = 8400 - 84*lr;
            int d0a = (lane + base) % 100;
            int d0b = (lane + 50 + base) % 100;
            int qa = (lr*384 + d0a) / 100;
            int qb = (lr*384 + d0b) / 100;
            float ka0 = b2f(kr[d0a]), ka1 = b2f(kr[d0a+100]), ka2 = b2f(kr[d0a+200]);
            float kb0 = b2f(kr[d0b]), kb1 = b2f(kr[d0b+100]), kb2 = b2f(kr[d0b+200]);
            sA0 += qpA[qa]*ka0 + qpA[qa+1]*ka1 + qpA[qa+2]*ka2;
            sB0 += qpB[qa]*ka0 + qpB[qa+1]*ka1 + qpB[qa+2]*ka2;
            sA1 += qpA[qb]*kb0 + qpA[qb+1]*kb1 + qpA[qb+2]*kb2;
            sB1 += qpB[qb]*kb0 + qpB[qb+1]*kb1 + qpB[qb+2]*kb2;
            if (d0a < 84) {
                float k3 = b2f(kr[d0a+300]);
                sA0 += qpA[qa+3]*k3; sB0 += qpB[qa+3]*k3;
            }
            if (d0b < 84) {
                float k3 = b2f(kr[d0b+300]);
                sA1 += qpA[qb+3]*k3; sB1 += qpB[qb+3]*k3;
            }
        }

        // pred dot for this row from registers: Hsrc[u] . GI[tgt]
        {
            float p = 0.f, n = 0.f;
            float lo0 = b2f(hc0 & 0xffff), hi0 = b2f(hc0 >> 16);
            float lo1 = b2f(hc1 & 0xffff), hi1 = b2f(hc1 >> 16);
            float lo2 = b2f(hc2 & 0xffff), hi2 = b2f(hc2 >> 16);
            p = lo0*gvp[0] + hi0*gvp[1] + lo1*gvp[2] + hi1*gvp[3] + lo2*gvp[4] + hi2*gvp[5];
            n = lo0*gvn[0] + hi0*gvn[1] + lo1*gvn[2] + hi1*gvn[3] + lo2*gvn[4] + hi2*gvn[5];
            #pragma unroll
            for (int d = 1; d < 64; d <<= 1) { p += __shfl_xor(p, d); n += __shfl_xor(n, d); }
            if (lane == 0) { dotP[lr] = p; dotN[lr] = n; }
        }

        // commit next row: K -> LDS (other buffer), H -> current regs
        if (r < 24) {
            uint32* kb = (uint32*)rowK[w*2 + (buf ^ 1)];
            kb[lane*3] = kn0; kb[lane*3+1] = kn1; kb[lane*3+2] = kn2;
            hc0 = hn0; hc1 = hn1; hc2 = hn2;
        }
    }

    if (lane < 50) {
        sred[w][0][lane]      = sA0;
        sred[w][0][lane + 50] = sA1;
        sred[w][1][lane]      = sB0;
        sred[w][1][lane + 50] = sB1;
    }
    __syncthreads();

    // finish: wave0 -> pos, wave1 -> neg
    if (w < 2) {
        const float* dptr = (w == 0) ? dotP : dotN;
        float den = 0.f, num = 0.f;
        #pragma unroll
        for (int t = 0; t < 2; t++) {
            int bin = lane + t*64;
            if (bin < HIST) {
                float s = sred[0][w][bin] + sred[1][w][bin] + sred[2][w][bin] + sred[3][w][bin];
                float e = __expf(s * inv_s3);
                if (w == 0 && userL[bin] == ii) e = 0.f;
                den += e; num += e * dptr[bin];
            }
        }
        #pragma unroll
        for (int d = 1; d < 64; d <<= 1) { den += __shfl_xor(den, d); num += __shfl_xor(num, d); }
        if (lane == 0) {
            float sc = sqrtf(den);   // den^BETA, and Sum(w)=sc
            if (w == 0) out[b]         = num/sc + sc*cvii;
            else        out[BATCH + b] = num/sc + sc*cvjj;
        }
    }
}

extern "C" void kernel_launch(void* const* d_in, const int* in_sizes, int n_in,
                              void* d_out, int out_size, void* d_ws, size_t ws_size,
                              hipStream_t stream)
{
    const int*   user     = (const int*)d_in[0];
    const int*   item_i   = (const int*)d_in[1];
    const int*   item_j   = (const int*)d_in[2];
    const float* emb_item = (const float*)d_in[3];
    const float* emb_in   = (const float*)d_in[4];
    const float* emb_out  = (const float*)d_in[5];
    const float* Wq = (const float*)d_in[6];
    const float* bq = (const float*)d_in[7];
    const float* Wk = (const float*)d_in[8];
    const float* bk = (const float*)d_in[9];
    const float* Wv = (const float*)d_in[10];
    const float* bv = (const float*)d_in[11];
    float* out = (float*)d_out;

    char* ws = (char*)d_ws;
    size_t off = 0;
    auto alloc = [&](size_t bytes) -> char* {
        char* p = ws + off;
        off = (off + bytes + 255) & ~(size_t)255;
        return p;
    };

    unsigned short* Qbf    = (unsigned short*)alloc((size_t)NPAD*C2*2);
    unsigned short* Hsrc   = (unsigned short*)alloc((size_t)N_IT*C3*2);
    unsigned short* WqB    = (unsigned short*)alloc((size_t)C3*C3*2);
    unsigned short* WkB    = (unsigned short*)alloc((size_t)C3*C3*2);
    unsigned short* WvTB   = (unsigned short*)alloc((size_t)C3*C3*2);
    unsigned short* KE     = (unsigned short*)alloc((size_t)N_IT*C3*2);
    float* QI              = (float*)alloc((size_t)N_IT*C3*4);
    float* GI              = (float*)alloc((size_t)N_IT*C3*4);
    float* cvI             = (float*)alloc((size_t)N_IT*4);
    float* Gpart           = (float*)alloc((size_t)NS*NTRI*4096*4);
    float* qsp             = (float*)alloc((size_t)NS*C2*4);
    unsigned short* GTswB  = (unsigned short*)alloc((size_t)C2*C2*2);
    float* qsumF           = (float*)alloc((size_t)C2*4);
    (void)ws_size;

    // 1) prep: bf16 copies (vectorized x8)
    {
        int total8 = NPAD*C2/8 + 3*(C3*C3/8) + N_IT*DH/8;
        prep_kernel<<<(total8 + 255)/256, 256, 0, stream>>>(emb_in, emb_out, emb_item,
                                                            Wq, Wk, Wv, Qbf, WqB, WkB, WvTB, Hsrc);
    }
    // 2) G = Q^T Q partials (f32 exact, triangle) + qsum partials
    gpart_kernel<<<NTRI*NS, 256, 0, stream>>>(emb_in, emb_out, Gpart, qsp);
    // 3) combine -> GTswB bf16, qsumF
    gcomb_kernel<<<257, 256, 0, stream>>>(Gpart, qsp, GTswB, qsumF);
    // 4) region -> Hsrc[:,128:384] (D fused in)
    gemmy_kernel<<<NPAD/64, 256, 0, stream>>>(Qbf, GTswB, qsumF, Hsrc);
    // 5) per-item fused: cvI + KE/QI/GI GEMMs
    item_kernel<<<157, 256, 0, stream>>>(Hsrc, WkB, WqB, WvTB, bk, bq, bv, KE, QI, GI, cvI);
    // 6) per-batch light kernel
    batchC_kernel<<<BATCH, 256, 0, stream>>>(user, item_i, item_j, KE, QI, GI, cvI, Hsrc, out);
}

// Round 7
// 125.172 us; speedup vs baseline: 2.2571x; 2.2571x over previous
//
#include <hip/hip_runtime.h>
#include <stdint.h>

#define N_IT 10000
#define NPAD 10048          // 157*64
#define DH 128
#define C2 256
#define C3 384
#define BATCH 1024
#define HIST 100
#define NS 50               // k-splits for G partials (200 rows each)
#define NTRI 10             // upper-triangle 64x64 tiles of G

typedef __attribute__((ext_vector_type(2))) float f32x2;
typedef __attribute__((ext_vector_type(4))) float f32x4;
typedef __attribute__((ext_vector_type(8))) short s16x8;
typedef unsigned int uint32;

__device__ __forceinline__ unsigned short f2b(float x){
    union { float f; uint32_t u; } v; v.f = x;
    uint32_t r = (v.u + 0x7FFF + ((v.u >> 16) & 1)) >> 16;
    return (unsigned short)r;
}
__device__ __forceinline__ float b2f(unsigned short u){
    union { uint32_t u; float f; } v; v.u = ((uint32_t)u) << 16;
    return v.f;
}

// ---------------- prep: bf16 copies, 8 elems/thread ----------------
__global__ void prep_kernel(const float* __restrict__ emb_in, const float* __restrict__ emb_out,
                            const float* __restrict__ emb_item,
                            const float* __restrict__ Wq, const float* __restrict__ Wk,
                            const float* __restrict__ Wv,
                            unsigned short* __restrict__ Qbf,
                            unsigned short* __restrict__ WqB, unsigned short* __restrict__ WkB,
                            unsigned short* __restrict__ WvTB, unsigned short* __restrict__ Hsrc)
{
    int idx = blockIdx.x * 256 + threadIdx.x;
    const int nQ8 = NPAD*C2/8;      // 321536
    const int nW8 = C3*C3/8;        // 18432
    const int nH8 = N_IT*DH/8;      // 160000
    if (idx < nQ8) {
        int i = idx >> 5, c8 = (idx & 31) * 8;
        int sr = min(i, N_IT-1);
        const float* src = (c8 < DH) ? (emb_in + (size_t)sr*DH + c8)
                                     : (emb_out + (size_t)sr*DH + (c8-DH));
        f32x4 a = *(const f32x4*)src, b = *(const f32x4*)(src+4);
        s16x8 o;
        #pragma unroll
        for (int k = 0; k < 4; k++) { o[k] = (short)f2b(a[k]); o[4+k] = (short)f2b(b[k]); }
        *(s16x8*)(Qbf + (size_t)idx*8) = o;
    } else if (idx < nQ8 + 2*nW8) {
        int t = idx - nQ8;
        int m = t / nW8, r8 = (t % nW8) * 8;
        const float* src = (m == 0) ? (Wq + r8) : (Wk + r8);
        unsigned short* dst = (m == 0) ? WqB : WkB;
        f32x4 a = *(const f32x4*)src, b = *(const f32x4*)(src+4);
        s16x8 o;
        #pragma unroll
        for (int k = 0; k < 4; k++) { o[k] = (short)f2b(a[k]); o[4+k] = (short)f2b(b[k]); }
        *(s16x8*)(dst + r8) = o;
    } else if (idx < nQ8 + 3*nW8) {
        int t = (idx - nQ8 - 2*nW8) * 8;    // flat index into WvTB
        int e = t / C3, d0 = t % C3;
        s16x8 o;
        #pragma unroll
        for (int k = 0; k < 8; k++) o[k] = (short)f2b(Wv[(size_t)(d0+k)*C3 + e]);
        *(s16x8*)(WvTB + t) = o;
    } else if (idx < nQ8 + 3*nW8 + nH8) {
        int t = idx - nQ8 - 3*nW8;
        int i = t >> 4, c8 = (t & 15) * 8;
        const float* src = emb_item + (size_t)i*DH + c8;
        f32x4 a = *(const f32x4*)src, b = *(const f32x4*)(src+4);
        s16x8 o;
        #pragma unroll
        for (int k = 0; k < 4; k++) { o[k] = (short)f2b(a[k]); o[4+k] = (short)f2b(b[k]); }
        *(s16x8*)(Hsrc + (size_t)i*C3 + c8) = o;
    }
}

// ---------------- G partials: G = Q^T Q (f32), 10 tri-tiles x 50 k-splits ----------------
__global__ void gpart_kernel(const float* __restrict__ emb_in, const float* __restrict__ emb_out,
                             float* __restrict__ Gpart, float* __restrict__ qsp)
{
    __shared__ float QA[8][64], QB[8][64];
    int bid = blockIdx.x;
    int split = bid % NS;
    int tile  = bid / NS;          // 0..9 upper triangle
    int ta = (tile < 4) ? 0 : (tile < 7) ? 1 : (tile < 9) ? 2 : 3;
    const int base_[4] = {0, 4, 7, 9};
    int tb = tile - base_[ta] + ta;
    int tid = threadIdx.x;
    int ty = tid >> 4, tx = tid & 15;

    const float* srcA = (ta < 2) ? (emb_in + ta*64) : (emb_out + (ta-2)*64);
    const float* srcB = (tb < 2) ? (emb_in + tb*64) : (emb_out + (tb-2)*64);

    float g[4][4];
    #pragma unroll
    for (int r = 0; r < 4; r++)
        #pragma unroll
        for (int c = 0; c < 4; c++) g[r][c] = 0.f;
    float qs = 0.f;

    int r0 = split * 200;
    int rr = tid >> 5, c2 = (tid & 31) * 2;
    for (int ch = 0; ch < 25; ch++) {
        int rows = r0 + ch*8;
        *(f32x2*)&QA[rr][c2] = *(const f32x2*)&srcA[(size_t)(rows+rr)*DH + c2];
        *(f32x2*)&QB[rr][c2] = *(const f32x2*)&srcB[(size_t)(rows+rr)*DH + c2];
        __syncthreads();
        #pragma unroll
        for (int k = 0; k < 8; k++) {
            f32x4 a = *(const f32x4*)&QA[k][ty*4];
            f32x4 b = *(const f32x4*)&QB[k][tx*4];
            #pragma unroll
            for (int r = 0; r < 4; r++)
                #pragma unroll
                for (int c = 0; c < 4; c++) g[r][c] += a[r]*b[c];
        }
        if (ta == tb && tid < 64) {
            #pragma unroll
            for (int k = 0; k < 8; k++) qs += QA[k][tid];
        }
        __syncthreads();
    }

    float* gout = Gpart + ((size_t)(split*NTRI + tile) << 12);
    #pragma unroll
    for (int r = 0; r < 4; r++)
        #pragma unroll
        for (int c = 0; c < 4; c++)
            gout[(ty*4 + r)*64 + tx*4 + c] = g[r][c];
    if (ta == tb && tid < 64) qsp[split*C2 + ta*64 + tid] = qs;
}

// ---------------- combine G partials -> GTswB bf16 [e][d] = G[d^128][e]; qsumF ----------------
__global__ void gcomb_kernel(const float* __restrict__ Gpart, const float* __restrict__ qsp,
                             unsigned short* __restrict__ GTswB, float* __restrict__ qsumF)
{
    int bid = blockIdx.x, tid = threadIdx.x;
    if (bid < 256) {
        int d = bid, e = tid;
        int ta = d >> 6, dl = d & 63, tb = e >> 6, el = e & 63;
        const int base_[4] = {0, 4, 7, 9};
        int tile, ro, co;
        if (ta <= tb) { tile = base_[ta] + (tb - ta); ro = dl; co = el; }
        else          { tile = base_[tb] + (ta - tb); ro = el; co = dl; }
        float s = 0.f;
        for (int sp = 0; sp < NS; sp++)
            s += Gpart[((size_t)(sp*NTRI + tile) << 12) + ro*64 + co];
        GTswB[e*C2 + (d ^ 128)] = f2b(s);
    } else {
        float s = 0.f;
        for (int sp = 0; sp < NS; sp++) s += qsp[sp*C2 + tid];
        qsumF[tid] = s;
    }
}

// ---------------- region GEMM (+fused D) -> Hsrc[:,128:384] bf16 ----------------
__global__ __launch_bounds__(256, 2) void gemmy_kernel(
    const unsigned short* __restrict__ Qbf, const unsigned short* __restrict__ GTswB,
    const float* __restrict__ qsumF, unsigned short* __restrict__ Hsrc)
{
    __shared__ __align__(16) unsigned short As[64*C2];  // 32KB swizzled
    __shared__ float ksumL[C2];
    __shared__ float Dl[64];
    int tid = threadIdx.x;
    int bm = blockIdx.x;

    #pragma unroll
    for (int p = 0; p < 8; p++) {
        int ch = tid + p*256;
        int r = ch >> 5, ci = ch & 31;
        s16x8 v = *(const s16x8*)(Qbf + (size_t)(bm*64 + r)*C2 + ci*8);
        *(s16x8*)((char*)As + r*512 + ((ci*16) ^ ((r&7)<<4))) = v;
    }
    ksumL[tid] = qsumF[tid ^ 128];
    __syncthreads();

    int w = tid >> 6, l = tid & 63, lm = l & 15, lq = l >> 4;

    // fused D phase: D[r] = N + (q_r . ksum)/16
    {
        float k0 = ksumL[l*4], k1 = ksumL[l*4+1], k2 = ksumL[l*4+2], k3 = ksumL[l*4+3];
        for (int i = 0; i < 16; i++) {
            int r = w*16 + i;
            const char* p = (const char*)As + r*512 + ((((l>>1)*16) ^ ((r&7)<<4)) + (l&1)*8);
            uint32 u0 = *(const uint32*)p, u1 = *(const uint32*)(p+4);
            float acc = b2f(u0 & 0xffff)*k0 + b2f(u0 >> 16)*k1
                      + b2f(u1 & 0xffff)*k2 + b2f(u1 >> 16)*k3;
            #pragma unroll
            for (int d = 1; d < 64; d <<= 1) acc += __shfl_xor(acc, d);
            if (l == 0) Dl[r] = (float)N_IT + acc * 0.0625f;
        }
    }
    __syncthreads();

    f32x4 acc[4][4];
    #pragma unroll
    for (int j = 0; j < 4; j++)
        #pragma unroll
        for (int m = 0; m < 4; m++) acc[j][m] = (f32x4){0,0,0,0};

    for (int kk = 0; kk < 8; kk++) {
        s16x8 a[4];
        #pragma unroll
        for (int m = 0; m < 4; m++) {
            int r = m*16 + lm;
            a[m] = *(const s16x8*)((char*)As + r*512 + ((64*kk + 16*lq) ^ ((r&7)<<4)));
        }
        #pragma unroll
        for (int j = 0; j < 4; j++) {
            int n = w*64 + j*16 + lm;
            s16x8 bf = *(const s16x8*)(GTswB + (size_t)n*C2 + kk*32 + lq*8);
            #pragma unroll
            for (int m = 0; m < 4; m++)
                acc[j][m] = __builtin_amdgcn_mfma_f32_16x16x32_bf16(a[m], bf, acc[j][m], 0,0,0);
        }
    }
    #pragma unroll
    for (int j = 0; j < 4; j++) {
        int col = w*64 + j*16 + lm;
        float qv = qsumF[col];
        #pragma unroll
        for (int m = 0; m < 4; m++)
            #pragma unroll
            for (int r = 0; r < 4; r++) {
                int row = bm*64 + m*16 + lq*4 + r;
                if (row < N_IT) {
                    float v = (qv + acc[j][m][r] * 0.0625f) / Dl[m*16 + lq*4 + r];
                    Hsrc[(size_t)row*C3 + DH + col] = f2b(v);
                }
            }
    }
}

// ---------------- item GEMMs: KE (all items) ; QT/GT (gathered 2048 targets) ----------------
__global__ __launch_bounds__(256, 2) void item_kernel(
    const unsigned short* __restrict__ Hsrc,
    const unsigned short* __restrict__ WkB, const unsigned short* __restrict__ WqB,
    const unsigned short* __restrict__ WvTB,
    const float* __restrict__ bk, const float* __restrict__ bq,
    const int* __restrict__ item_i, const int* __restrict__ item_j,
    unsigned short* __restrict__ KE, float* __restrict__ QT, float* __restrict__ GT)
{
    __shared__ __align__(16) unsigned short As[64*C3];  // 48KB swizzled
    __shared__ int rid[64];
    int tid = threadIdx.x;
    int bid = blockIdx.x;
    int mm, bm;
    if (bid < 157)      { mm = 0; bm = bid; }
    else if (bid < 189) { mm = 1; bm = bid - 157; }
    else                { mm = 2; bm = bid - 189; }
    const unsigned short* Bm = (mm == 0) ? WkB : (mm == 1) ? WqB : WvTB;

    if (tid < 64) {
        int idx = bm*64 + tid;
        int u;
        if (mm == 0) u = min(idx, N_IT-1);
        else u = (idx < BATCH) ? item_i[idx] : item_j[idx - BATCH];
        rid[tid] = u;
    }
    __syncthreads();

    for (int ch = tid; ch < 64*48; ch += 256) {
        int r = ch / 48, ci = ch % 48;
        s16x8 v = *(const s16x8*)(Hsrc + (size_t)rid[r]*C3 + ci*8);
        *(s16x8*)((char*)As + r*768 + ((ci*16) ^ ((r&7)<<4))) = v;
    }
    __syncthreads();

    int w = tid >> 6, l = tid & 63, lm = l & 15, lq = l >> 4;
    f32x4 acc[6][4];
    #pragma unroll
    for (int j = 0; j < 6; j++)
        #pragma unroll
        for (int m = 0; m < 4; m++) acc[j][m] = (f32x4){0,0,0,0};

    for (int kk = 0; kk < 12; kk++) {
        s16x8 a[4];
        #pragma unroll
        for (int m = 0; m < 4; m++) {
            int r = m*16 + lm;
            a[m] = *(const s16x8*)((char*)As + r*768 + ((64*kk + 16*lq) ^ ((r&7)<<4)));
        }
        #pragma unroll
        for (int j = 0; j < 6; j++) {
            int n = (w*6 + j)*16 + lm;
            s16x8 bf = *(const s16x8*)(Bm + (size_t)n*C3 + kk*32 + lq*8);
            #pragma unroll
            for (int m = 0; m < 4; m++)
                acc[j][m] = __builtin_amdgcn_mfma_f32_16x16x32_bf16(a[m], bf, acc[j][m], 0,0,0);
        }
    }
    #pragma unroll
    for (int j = 0; j < 6; j++) {
        int col = (w*6 + j)*16 + lm;
        float bias = (mm == 0) ? bk[col] : (mm == 1) ? bq[col] : 0.f;
        #pragma unroll
        for (int m = 0; m < 4; m++)
            #pragma unroll
            for (int r = 0; r < 4; r++) {
                int row = bm*64 + m*16 + lq*4 + r;
                float v = acc[j][m][r] + bias;
                if (mm == 0) {
                    if (row < N_IT) KE[(size_t)row*C3 + col] = f2b(v);
                } else if (mm == 1) QT[(size_t)row*C3 + col] = v;
                else                GT[(size_t)row*C3 + col] = v;
            }
    }
}

// ---------------- per-batch: row-once gather, quirk-binned scores, tiny LDS ----------------
__global__ __launch_bounds__(256, 4) void batchC_kernel(
    const int* __restrict__ user, const int* __restrict__ item_i, const int* __restrict__ item_j,
    const unsigned short* __restrict__ KE, const float* __restrict__ QT,
    const float* __restrict__ GT, const float* __restrict__ bv,
    const unsigned short* __restrict__ Hsrc, float* __restrict__ out)
{
    __shared__ unsigned short rowK[8][C3];     // per-wave double-buffered K row (6 KB)
    __shared__ float qpA[C3], qpB[C3];         // 3 KB
    __shared__ int userL[HIST];
    __shared__ float dotP[HIST], dotN[HIST];
    __shared__ float sred[4][2][HIST];         // 3.2 KB
    __shared__ float cvv[2];

    int b = blockIdx.x, tid = threadIdx.x;
    int w = tid >> 6, lane = tid & 63;
    int ii = item_i[b], jj = item_j[b];

    if (tid < HIST) userL[tid] = user[b*HIST + tid];
    qpA[tid] = QT[(size_t)b*C3 + tid];
    qpB[tid] = QT[(size_t)(BATCH + b)*C3 + tid];
    if (tid < 128) {
        qpA[256 + tid] = QT[(size_t)b*C3 + 256 + tid];
        qpB[256 + tid] = QT[(size_t)(BATCH + b)*C3 + 256 + tid];
    }
    float gvp[6], gvn[6];
    #pragma unroll
    for (int k = 0; k < 6; k++) {
        gvp[k] = GT[(size_t)b*C3 + lane*6 + k];
        gvn[k] = GT[(size_t)(BATCH + b)*C3 + lane*6 + k];
    }
    // cv = Hsrc[tgt].bv  (waves 2/3)
    if (w >= 2) {
        int tg = (w == 2) ? ii : jj;
        const uint32* hp = (const uint32*)(Hsrc + (size_t)tg*C3) + lane*3;
        uint32 a = hp[0], b_ = hp[1], c = hp[2];
        float p = b2f(a & 0xffff)*bv[lane*6]   + b2f(a >> 16)*bv[lane*6+1]
                + b2f(b_ & 0xffff)*bv[lane*6+2] + b2f(b_ >> 16)*bv[lane*6+3]
                + b2f(c & 0xffff)*bv[lane*6+4] + b2f(c >> 16)*bv[lane*6+5];
        #pragma unroll
        for (int d = 1; d < 64; d <<= 1) p += __shfl_xor(p, d);
        if (lane == 0) cvv[w - 2] = p;
    }
    __syncthreads();

    // prologue: stage row 0 of this wave
    uint32 hc0, hc1, hc2;
    {
        int u = userL[w*25];
        const uint32* kp = (const uint32*)(KE + (size_t)u*C3) + lane*3;
        const uint32* hp = (const uint32*)(Hsrc + (size_t)u*C3) + lane*3;
        uint32 k0 = kp[0], k1 = kp[1], k2 = kp[2];
        hc0 = hp[0]; hc1 = hp[1]; hc2 = hp[2];
        uint32* kb = (uint32*)rowK[w*2];
        kb[lane*3] = k0; kb[lane*3+1] = k1; kb[lane*3+2] = k2;
    }

    float sA0 = 0.f, sA1 = 0.f, sB0 = 0.f, sB1 = 0.f;
    const float inv_s3 = 0.05103103630798287f;  // 1/sqrt(384)

    for (int r = 0; r < 25; r++) {
        int lr = w*25 + r;
        int buf = r & 1;

        // prefetch next row into registers (latency hides under compute)
        uint32 kn0=0, kn1=0, kn2=0, hn0=0, hn1=0, hn2=0;
        if (r < 24) {
            int u = userL[lr + 1];
            const uint32* kp = (const uint32*)(KE + (size_t)u*C3) + lane*3;
            const uint32* hp = (const uint32*)(Hsrc + (size_t)u*C3) + lane*3;
            kn0 = kp[0]; kn1 = kp[1]; kn2 = kp[2];
            hn0 = hp[0]; hn1 = hp[1]; hn2 = hp[2];
        }

        // scores: quirk bins. flat = lr*384 + d''; bin = flat%100; q idx = flat/100
        if (lane < 50) {
            const unsigned short* kr = rowK[w*2 + buf];
            int base = 8400 - 84*lr;
            int d0a = (lane + base) % 100;
            int d0b = (lane + 50 + base) % 100;
            int qa = (lr*384 + d0a) / 100;
            int qb = (lr*384 + d0b) / 100;
            float ka0 = b2f(kr[d0a]), ka1 = b2f(kr[d0a+100]), ka2 = b2f(kr[d0a+200]);
            float kb0 = b2f(kr[d0b]), kb1 = b2f(kr[d0b+100]), kb2 = b2f(kr[d0b+200]);
            sA0 += qpA[qa]*ka0 + qpA[qa+1]*ka1 + qpA[qa+2]*ka2;
            sB0 += qpB[qa]*ka0 + qpB[qa+1]*ka1 + qpB[qa+2]*ka2;
            sA1 += qpA[qb]*kb0 + qpA[qb+1]*kb1 + qpA[qb+2]*kb2;
            sB1 += qpB[qb]*kb0 + qpB[qb+1]*kb1 + qpB[qb+2]*kb2;
            if (d0a < 84) {
                float k3 = b2f(kr[d0a+300]);
                sA0 += qpA[qa+3]*k3; sB0 += qpB[qa+3]*k3;
            }
            if (d0b < 84) {
                float k3 = b2f(kr[d0b+300]);
                sA1 += qpA[qb+3]*k3; sB1 += qpB[qb+3]*k3;
            }
        }

        // pred dot for this row from registers: Hsrc[u] . GT row
        {
            float p = 0.f, n = 0.f;
            float lo0 = b2f(hc0 & 0xffff), hi0 = b2f(hc0 >> 16);
            float lo1 = b2f(hc1 & 0xffff), hi1 = b2f(hc1 >> 16);
            float lo2 = b2f(hc2 & 0xffff), hi2 = b2f(hc2 >> 16);
            p = lo0*gvp[0] + hi0*gvp[1] + lo1*gvp[2] + hi1*gvp[3] + lo2*gvp[4] + hi2*gvp[5];
            n = lo0*gvn[0] + hi0*gvn[1] + lo1*gvn[2] + hi1*gvn[3] + lo2*gvn[4] + hi2*gvn[5];
            #pragma unroll
            for (int d = 1; d < 64; d <<= 1) { p += __shfl_xor(p, d); n += __shfl_xor(n, d); }
            if (lane == 0) { dotP[lr] = p; dotN[lr] = n; }
        }

        // commit next row: K -> LDS (other buffer), H -> current regs
        if (r < 24) {
            uint32* kb = (uint32*)rowK[w*2 + (buf ^ 1)];
            kb[lane*3] = kn0; kb[lane*3+1] = kn1; kb[lane*3+2] = kn2;
            hc0 = hn0; hc1 = hn1; hc2 = hn2;
        }
    }

    if (lane < 50) {
        sred[w][0][lane]      = sA0;
        sred[w][0][lane + 50] = sA1;
        sred[w][1][lane]      = sB0;
        sred[w][1][lane + 50] = sB1;
    }
    __syncthreads();

    // finish: wave0 -> pos, wave1 -> neg
    if (w < 2) {
        const float* dptr = (w == 0) ? dotP : dotN;
        float den = 0.f, num = 0.f;
        #pragma unroll
        for (int t = 0; t < 2; t++) {
            int bin = lane + t*64;
            if (bin < HIST) {
                float s = sred[0][w][bin] + sred[1][w][bin] + sred[2][w][bin] + sred[3][w][bin];
                float e = __expf(s * inv_s3);
                if (w == 0 && userL[bin] == ii) e = 0.f;
                den += e; num += e * dptr[bin];
            }
        }
        #pragma unroll
        for (int d = 1; d < 64; d <<= 1) { den += __shfl_xor(den, d); num += __shfl_xor(num, d); }
        if (lane == 0) {
            float sc = sqrtf(den);   // den^BETA, and Sum(w)=sc
            if (w == 0) out[b]         = num/sc + sc*cvv[0];
            else        out[BATCH + b] = num/sc + sc*cvv[1];
        }
    }
}

extern "C" void kernel_launch(void* const* d_in, const int* in_sizes, int n_in,
                              void* d_out, int out_size, void* d_ws, size_t ws_size,
                              hipStream_t stream)
{
    const int*   user     = (const int*)d_in[0];
    const int*   item_i   = (const int*)d_in[1];
    const int*   item_j   = (const int*)d_in[2];
    const float* emb_item = (const float*)d_in[3];
    const float* emb_in   = (const float*)d_in[4];
    const float* emb_out  = (const float*)d_in[5];
    const float* Wq = (const float*)d_in[6];
    const float* bq = (const float*)d_in[7];
    const float* Wk = (const float*)d_in[8];
    const float* bk = (const float*)d_in[9];
    const float* Wv = (const float*)d_in[10];
    const float* bv = (const float*)d_in[11];
    float* out = (float*)d_out;

    char* ws = (char*)d_ws;
    size_t off = 0;
    auto alloc = [&](size_t bytes) -> char* {
        char* p = ws + off;
        off = (off + bytes + 255) & ~(size_t)255;
        return p;
    };

    unsigned short* Qbf    = (unsigned short*)alloc((size_t)NPAD*C2*2);
    unsigned short* Hsrc   = (unsigned short*)alloc((size_t)N_IT*C3*2);
    unsigned short* WqB    = (unsigned short*)alloc((size_t)C3*C3*2);
    unsigned short* WkB    = (unsigned short*)alloc((size_t)C3*C3*2);
    unsigned short* WvTB   = (unsigned short*)alloc((size_t)C3*C3*2);
    unsigned short* KE     = (unsigned short*)alloc((size_t)N_IT*C3*2);
    float* QT              = (float*)alloc((size_t)2*BATCH*C3*4);
    float* GT              = (float*)alloc((size_t)2*BATCH*C3*4);
    float* Gpart           = (float*)alloc((size_t)NS*NTRI*4096*4);
    float* qsp             = (float*)alloc((size_t)NS*C2*4);
    unsigned short* GTswB  = (unsigned short*)alloc((size_t)C2*C2*2);
    float* qsumF           = (float*)alloc((size_t)C2*4);
    (void)ws_size;

    // 1) prep: bf16 copies (vectorized x8)
    {
        int total8 = NPAD*C2/8 + 3*(C3*C3/8) + N_IT*DH/8;
        prep_kernel<<<(total8 + 255)/256, 256, 0, stream>>>(emb_in, emb_out, emb_item,
                                                            Wq, Wk, Wv, Qbf, WqB, WkB, WvTB, Hsrc);
    }
    // 2) G = Q^T Q partials (f32 exact, triangle) + qsum partials
    gpart_kernel<<<NTRI*NS, 256, 0, stream>>>(emb_in, emb_out, Gpart, qsp);
    // 3) combine -> GTswB bf16, qsumF
    gcomb_kernel<<<257, 256, 0, stream>>>(Gpart, qsp, GTswB, qsumF);
    // 4) region -> Hsrc[:,128:384] (D fused in)
    gemmy_kernel<<<NPAD/64, 256, 0, stream>>>(Qbf, GTswB, qsumF, Hsrc);
    // 5) item GEMMs: KE all items; QT/GT gathered targets only
    item_kernel<<<221, 256, 0, stream>>>(Hsrc, WkB, WqB, WvTB, bk, bq, item_i, item_j,
                                         KE, QT, GT);
    // 6) per-batch light kernel (cv fused in)
    batchC_kernel<<<BATCH, 256, 0, stream>>>(user, item_i, item_j, KE, QT, GT, bv, Hsrc, out);
}

// Round 8
// 114.993 us; speedup vs baseline: 2.4569x; 1.0885x over previous
//
#include <hip/hip_runtime.h>
#include <stdint.h>

#define N_IT 10000
#define NPAD 10048          // 157*64
#define DH 128
#define C2 256
#define C3 384
#define BATCH 1024
#define HIST 100
#define NS 50               // k-splits for G partials (200 rows each)
#define NTRI 10             // upper-triangle 64x64 tiles of G

typedef __attribute__((ext_vector_type(2))) float f32x2;
typedef __attribute__((ext_vector_type(4))) float f32x4;
typedef __attribute__((ext_vector_type(8))) short s16x8;
typedef unsigned int uint32;

__device__ __forceinline__ unsigned short f2b(float x){
    union { float f; uint32_t u; } v; v.f = x;
    uint32_t r = (v.u + 0x7FFF + ((v.u >> 16) & 1)) >> 16;
    return (unsigned short)r;
}
__device__ __forceinline__ float b2f(unsigned short u){
    union { uint32_t u; float f; } v; v.u = ((uint32_t)u) << 16;
    return v.f;
}

// ---------------- fused A: gpart (blocks 0..499) + prep (blocks 500..2596) ----------------
__global__ void fusedA_kernel(const float* __restrict__ emb_in, const float* __restrict__ emb_out,
                              const float* __restrict__ emb_item,
                              const float* __restrict__ Wq, const float* __restrict__ Wk,
                              const float* __restrict__ Wv,
                              unsigned short* __restrict__ Qbf,
                              unsigned short* __restrict__ WqB, unsigned short* __restrict__ WkB,
                              unsigned short* __restrict__ WvTB, unsigned short* __restrict__ Hsrc,
                              float* __restrict__ Gpart, float* __restrict__ qsp)
{
    __shared__ float QA[8][64], QB[8][64];
    int tid = threadIdx.x;

    if (blockIdx.x < NTRI*NS) {
        // ---- gpart: G = Q^T Q (f32), 10 tri-tiles x 50 k-splits ----
        int bid = blockIdx.x;
        int split = bid % NS;
        int tile  = bid / NS;
        int ta = (tile < 4) ? 0 : (tile < 7) ? 1 : (tile < 9) ? 2 : 3;
        const int base_[4] = {0, 4, 7, 9};
        int tb = tile - base_[ta] + ta;
        int ty = tid >> 4, tx = tid & 15;

        const float* srcA = (ta < 2) ? (emb_in + ta*64) : (emb_out + (ta-2)*64);
        const float* srcB = (tb < 2) ? (emb_in + tb*64) : (emb_out + (tb-2)*64);

        float g[4][4];
        #pragma unroll
        for (int r = 0; r < 4; r++)
            #pragma unroll
            for (int c = 0; c < 4; c++) g[r][c] = 0.f;
        float qs = 0.f;

        int r0 = split * 200;
        int rr = tid >> 5, c2 = (tid & 31) * 2;
        for (int ch = 0; ch < 25; ch++) {
            int rows = r0 + ch*8;
            *(f32x2*)&QA[rr][c2] = *(const f32x2*)&srcA[(size_t)(rows+rr)*DH + c2];
            *(f32x2*)&QB[rr][c2] = *(const f32x2*)&srcB[(size_t)(rows+rr)*DH + c2];
            __syncthreads();
            #pragma unroll
            for (int k = 0; k < 8; k++) {
                f32x4 a = *(const f32x4*)&QA[k][ty*4];
                f32x4 b = *(const f32x4*)&QB[k][tx*4];
                #pragma unroll
                for (int r = 0; r < 4; r++)
                    #pragma unroll
                    for (int c = 0; c < 4; c++) g[r][c] += a[r]*b[c];
            }
            if (ta == tb && tid < 64) {
                #pragma unroll
                for (int k = 0; k < 8; k++) qs += QA[k][tid];
            }
            __syncthreads();
        }

        float* gout = Gpart + ((size_t)(split*NTRI + tile) << 12);
        #pragma unroll
        for (int r = 0; r < 4; r++)
            #pragma unroll
            for (int c = 0; c < 4; c++)
                gout[(ty*4 + r)*64 + tx*4 + c] = g[r][c];
        if (ta == tb && tid < 64) qsp[split*C2 + ta*64 + tid] = qs;
        return;
    }

    // ---- prep: bf16 copies, 8 elems/thread ----
    int idx = (blockIdx.x - NTRI*NS) * 256 + tid;
    const int nQ8 = NPAD*C2/8;      // 321536
    const int nW8 = C3*C3/8;        // 18432
    const int nH8 = N_IT*DH/8;      // 160000
    if (idx < nQ8) {
        int i = idx >> 5, c8 = (idx & 31) * 8;
        int sr = min(i, N_IT-1);
        const float* src = (c8 < DH) ? (emb_in + (size_t)sr*DH + c8)
                                     : (emb_out + (size_t)sr*DH + (c8-DH));
        f32x4 a = *(const f32x4*)src, b = *(const f32x4*)(src+4);
        s16x8 o;
        #pragma unroll
        for (int k = 0; k < 4; k++) { o[k] = (short)f2b(a[k]); o[4+k] = (short)f2b(b[k]); }
        *(s16x8*)(Qbf + (size_t)idx*8) = o;
    } else if (idx < nQ8 + 2*nW8) {
        int t = idx - nQ8;
        int m = t / nW8, r8 = (t % nW8) * 8;
        const float* src = (m == 0) ? (Wq + r8) : (Wk + r8);
        unsigned short* dst = (m == 0) ? WqB : WkB;
        f32x4 a = *(const f32x4*)src, b = *(const f32x4*)(src+4);
        s16x8 o;
        #pragma unroll
        for (int k = 0; k < 4; k++) { o[k] = (short)f2b(a[k]); o[4+k] = (short)f2b(b[k]); }
        *(s16x8*)(dst + r8) = o;
    } else if (idx < nQ8 + 3*nW8) {
        int t = (idx - nQ8 - 2*nW8) * 8;    // flat index into WvTB
        int e = t / C3, d0 = t % C3;
        s16x8 o;
        #pragma unroll
        for (int k = 0; k < 8; k++) o[k] = (short)f2b(Wv[(size_t)(d0+k)*C3 + e]);
        *(s16x8*)(WvTB + t) = o;
    } else if (idx < nQ8 + 3*nW8 + nH8) {
        int t = idx - nQ8 - 3*nW8;
        int i = t >> 4, c8 = (t & 15) * 8;
        const float* src = emb_item + (size_t)i*DH + c8;
        f32x4 a = *(const f32x4*)src, b = *(const f32x4*)(src+4);
        s16x8 o;
        #pragma unroll
        for (int k = 0; k < 4; k++) { o[k] = (short)f2b(a[k]); o[4+k] = (short)f2b(b[k]); }
        *(s16x8*)(Hsrc + (size_t)i*C3 + c8) = o;
    }
}

// ---------------- combine G partials -> GTswB bf16 [e][d] = G[d^128][e]; qsumF ----------------
__global__ void gcomb_kernel(const float* __restrict__ Gpart, const float* __restrict__ qsp,
                             unsigned short* __restrict__ GTswB, float* __restrict__ qsumF)
{
    int bid = blockIdx.x, tid = threadIdx.x;
    if (bid < 256) {
        int d = bid, e = tid;
        int ta = d >> 6, dl = d & 63, tb = e >> 6, el = e & 63;
        const int base_[4] = {0, 4, 7, 9};
        int tile, ro, co;
        if (ta <= tb) { tile = base_[ta] + (tb - ta); ro = dl; co = el; }
        else          { tile = base_[tb] + (ta - tb); ro = el; co = dl; }
        float s = 0.f;
        for (int sp = 0; sp < NS; sp++)
            s += Gpart[((size_t)(sp*NTRI + tile) << 12) + ro*64 + co];
        GTswB[e*C2 + (d ^ 128)] = f2b(s);
    } else {
        float s = 0.f;
        for (int sp = 0; sp < NS; sp++) s += qsp[sp*C2 + tid];
        qsumF[tid] = s;
    }
}

// ---------------- gemmyKE: region (+D) -> Hsrc[:,128:384] AND KE = H@Wk^T+bk (32-row tiles) ----------------
__global__ __launch_bounds__(256, 3) void gemmyKE_kernel(
    const unsigned short* __restrict__ Qbf, const unsigned short* __restrict__ GTswB,
    const float* __restrict__ qsumF, const unsigned short* __restrict__ WkB,
    const float* __restrict__ bk,
    unsigned short* __restrict__ Hsrc, unsigned short* __restrict__ KE)
{
    __shared__ __align__(16) unsigned short As[32*C2];  // 16KB swizzled, 512B rows
    __shared__ __align__(16) unsigned short Ht[32*C3];  // 24KB swizzled, 768B rows
    __shared__ float ksumL[C2];
    __shared__ float Dl[32];
    int tid = threadIdx.x;
    int r0 = blockIdx.x * 32;

    #pragma unroll
    for (int p = 0; p < 4; p++) {       // stage Q tile (32 rows x 256)
        int ch = tid + p*256;
        int r = ch >> 5, ci = ch & 31;
        s16x8 v = *(const s16x8*)(Qbf + (size_t)(r0 + r)*C2 + ci*8);
        *(s16x8*)((char*)As + r*512 + ((ci*16) ^ ((r&7)<<4))) = v;
    }
    #pragma unroll
    for (int p = 0; p < 2; p++) {       // stage H cols 0:128 (32 rows x 16 chunks)
        int ch = tid + p*256;
        int r = ch >> 4, ci = ch & 15;
        int row = min(r0 + r, N_IT-1);
        s16x8 v = *(const s16x8*)(Hsrc + (size_t)row*C3 + ci*8);
        *(s16x8*)((char*)Ht + r*768 + ((ci*16) ^ ((r&7)<<4))) = v;
    }
    ksumL[tid] = qsumF[tid ^ 128];
    __syncthreads();

    int w = tid >> 6, l = tid & 63, lm = l & 15, lq = l >> 4;

    // D phase: D[r] = N + (q_r . ksum)/16, rows 0..31
    {
        float k0 = ksumL[l*4], k1 = ksumL[l*4+1], k2 = ksumL[l*4+2], k3 = ksumL[l*4+3];
        for (int i = 0; i < 8; i++) {
            int r = w*8 + i;
            const char* p = (const char*)As + r*512 + ((((l>>1)*16) ^ ((r&7)<<4)) + (l&1)*8);
            uint32 u0 = *(const uint32*)p, u1 = *(const uint32*)(p+4);
            float acc = b2f(u0 & 0xffff)*k0 + b2f(u0 >> 16)*k1
                      + b2f(u1 & 0xffff)*k2 + b2f(u1 >> 16)*k3;
            #pragma unroll
            for (int d = 1; d < 64; d <<= 1) acc += __shfl_xor(acc, d);
            if (l == 0) Dl[r] = (float)N_IT + acc * 0.0625f;
        }
    }
    __syncthreads();

    // region MFMA: 256 cols, 32 rows
    {
        f32x4 acc[4][2];
        #pragma unroll
        for (int j = 0; j < 4; j++)
            #pragma unroll
            for (int m = 0; m < 2; m++) acc[j][m] = (f32x4){0,0,0,0};

        for (int kk = 0; kk < 8; kk++) {
            s16x8 a[2];
            #pragma unroll
            for (int m = 0; m < 2; m++) {
                int r = m*16 + lm;
                a[m] = *(const s16x8*)((char*)As + r*512 + ((64*kk + 16*lq) ^ ((r&7)<<4)));
            }
            #pragma unroll
            for (int j = 0; j < 4; j++) {
                int n = w*64 + j*16 + lm;
                s16x8 bf = *(const s16x8*)(GTswB + (size_t)n*C2 + kk*32 + lq*8);
                #pragma unroll
                for (int m = 0; m < 2; m++)
                    acc[j][m] = __builtin_amdgcn_mfma_f32_16x16x32_bf16(a[m], bf, acc[j][m], 0,0,0);
            }
        }
        #pragma unroll
        for (int j = 0; j < 4; j++) {
            int col = w*64 + j*16 + lm;
            float qv = qsumF[col];
            int c = DH + col;
            #pragma unroll
            for (int m = 0; m < 2; m++)
                #pragma unroll
                for (int r = 0; r < 4; r++) {
                    int lr = m*16 + lq*4 + r;
                    int row = r0 + lr;
                    float v = (qv + acc[j][m][r] * 0.0625f) / Dl[lr];
                    unsigned short bb = f2b(v);
                    if (row < N_IT) Hsrc[(size_t)row*C3 + c] = bb;
                    *(unsigned short*)((char*)Ht + lr*768 +
                        ((((c>>3)<<4)) ^ ((lr&7)<<4)) + (c&7)*2) = bb;
                }
        }
    }
    __syncthreads();

    // KE GEMM: A = Ht (full 384 cols), B = WkB
    {
        f32x4 acc[6][2];
        #pragma unroll
        for (int j = 0; j < 6; j++)
            #pragma unroll
            for (int m = 0; m < 2; m++) acc[j][m] = (f32x4){0,0,0,0};

        for (int kk = 0; kk < 12; kk++) {
            s16x8 a[2];
            #pragma unroll
            for (int m = 0; m < 2; m++) {
                int r = m*16 + lm;
                a[m] = *(const s16x8*)((char*)Ht + r*768 + ((64*kk + 16*lq) ^ ((r&7)<<4)));
            }
            #pragma unroll
            for (int j = 0; j < 6; j++) {
                int n = (w*6 + j)*16 + lm;
                s16x8 bf = *(const s16x8*)(WkB + (size_t)n*C3 + kk*32 + lq*8);
                #pragma unroll
                for (int m = 0; m < 2; m++)
                    acc[j][m] = __builtin_amdgcn_mfma_f32_16x16x32_bf16(a[m], bf, acc[j][m], 0,0,0);
            }
        }
        #pragma unroll
        for (int j = 0; j < 6; j++) {
            int col = (w*6 + j)*16 + lm;
            float bias = bk[col];
            #pragma unroll
            for (int m = 0; m < 2; m++)
                #pragma unroll
                for (int r = 0; r < 4; r++) {
                    int row = r0 + m*16 + lq*4 + r;
                    if (row < N_IT) KE[(size_t)row*C3 + col] = f2b(acc[j][m][r] + bias);
                }
        }
    }
}

// ---------------- tgtQG: QT = tgt@Wq^T+bq, GT = tgt@Wv (gathered 2048 target rows) ----------------
__global__ __launch_bounds__(256, 4) void tgtQG_kernel(
    const unsigned short* __restrict__ Hsrc,
    const unsigned short* __restrict__ WqB, const unsigned short* __restrict__ WvTB,
    const float* __restrict__ bq,
    const int* __restrict__ item_i, const int* __restrict__ item_j,
    float* __restrict__ QT, float* __restrict__ GT)
{
    __shared__ __align__(16) unsigned short As[32*C3];  // 24KB swizzled
    __shared__ int rid[32];
    int tid = threadIdx.x;
    int mm = blockIdx.x >> 6;       // 0: Wq->QT, 1: Wv->GT
    int bm = blockIdx.x & 63;
    const unsigned short* Bm = (mm == 0) ? WqB : WvTB;

    if (tid < 32) {
        int idx = bm*32 + tid;
        rid[tid] = (idx < BATCH) ? item_i[idx] : item_j[idx - BATCH];
    }
    __syncthreads();

    #pragma unroll
    for (int p = 0; p < 6; p++) {
        int ch = tid + p*256;
        int r = ch / 48, ci = ch % 48;
        s16x8 v = *(const s16x8*)(Hsrc + (size_t)rid[r]*C3 + ci*8);
        *(s16x8*)((char*)As + r*768 + ((ci*16) ^ ((r&7)<<4))) = v;
    }
    __syncthreads();

    int w = tid >> 6, l = tid & 63, lm = l & 15, lq = l >> 4;
    f32x4 acc[6][2];
    #pragma unroll
    for (int j = 0; j < 6; j++)
        #pragma unroll
        for (int m = 0; m < 2; m++) acc[j][m] = (f32x4){0,0,0,0};

    for (int kk = 0; kk < 12; kk++) {
        s16x8 a[2];
        #pragma unroll
        for (int m = 0; m < 2; m++) {
            int r = m*16 + lm;
            a[m] = *(const s16x8*)((char*)As + r*768 + ((64*kk + 16*lq) ^ ((r&7)<<4)));
        }
        #pragma unroll
        for (int j = 0; j < 6; j++) {
            int n = (w*6 + j)*16 + lm;
            s16x8 bf = *(const s16x8*)(Bm + (size_t)n*C3 + kk*32 + lq*8);
            #pragma unroll
            for (int m = 0; m < 2; m++)
                acc[j][m] = __builtin_amdgcn_mfma_f32_16x16x32_bf16(a[m], bf, acc[j][m], 0,0,0);
        }
    }
    float* Out = (mm == 0) ? QT : GT;
    #pragma unroll
    for (int j = 0; j < 6; j++) {
        int col = (w*6 + j)*16 + lm;
        float bias = (mm == 0) ? bq[col] : 0.f;
        #pragma unroll
        for (int m = 0; m < 2; m++)
            #pragma unroll
            for (int r = 0; r < 4; r++) {
                int row = bm*32 + m*16 + lq*4 + r;
                Out[(size_t)row*C3 + col] = acc[j][m][r] + bias;
            }
    }
}

// ---------------- per-batch: two-pass (scores | e | preds), no per-row reductions ----------------
__global__ __launch_bounds__(256, 4) void batchD_kernel(
    const int* __restrict__ user, const int* __restrict__ item_i, const int* __restrict__ item_j,
    const unsigned short* __restrict__ KE, const float* __restrict__ QT,
    const float* __restrict__ GT, const float* __restrict__ bv,
    const unsigned short* __restrict__ Hsrc, float* __restrict__ out)
{
    __shared__ unsigned short rowK[8][C3];     // per-wave double-buffered K row (6 KB)
    __shared__ float qpA[C3], qpB[C3];         // 3 KB
    __shared__ int userL[HIST];
    __shared__ float sred[4][2][HIST];         // 3.2 KB
    __shared__ float eL[2][HIST];              // 0.8 KB
    __shared__ float scal[2], cvv[2], red[4][2];

    int b = blockIdx.x, tid = threadIdx.x;
    int w = tid >> 6, lane = tid & 63;
    int ii = item_i[b], jj = item_j[b];

    if (tid < HIST) userL[tid] = user[b*HIST + tid];
    qpA[tid] = QT[(size_t)b*C3 + tid];
    qpB[tid] = QT[(size_t)(BATCH + b)*C3 + tid];
    if (tid < 128) {
        qpA[256 + tid] = QT[(size_t)b*C3 + 256 + tid];
        qpB[256 + tid] = QT[(size_t)(BATCH + b)*C3 + 256 + tid];
    }
    float gvp[6], gvn[6];
    #pragma unroll
    for (int k = 0; k < 6; k++) {
        gvp[k] = GT[(size_t)b*C3 + lane*6 + k];
        gvn[k] = GT[(size_t)(BATCH + b)*C3 + lane*6 + k];
    }
    // cv = Hsrc[tgt].bv  (waves 2/3)
    if (w >= 2) {
        int tg = (w == 2) ? ii : jj;
        const uint32* hp = (const uint32*)(Hsrc + (size_t)tg*C3) + lane*3;
        uint32 a = hp[0], b_ = hp[1], c = hp[2];
        float p = b2f(a & 0xffff)*bv[lane*6]   + b2f(a >> 16)*bv[lane*6+1]
                + b2f(b_ & 0xffff)*bv[lane*6+2] + b2f(b_ >> 16)*bv[lane*6+3]
                + b2f(c & 0xffff)*bv[lane*6+4] + b2f(c >> 16)*bv[lane*6+5];
        #pragma unroll
        for (int d = 1; d < 64; d <<= 1) p += __shfl_xor(p, d);
        if (lane == 0) cvv[w - 2] = p;
    }
    __syncthreads();

    // ---- pass 1: scores only (KE rows) ----
    {
        int u = userL[w*25];
        const uint32* kp = (const uint32*)(KE + (size_t)u*C3) + lane*3;
        uint32* kb = (uint32*)rowK[w*2];
        kb[lane*3] = kp[0]; kb[lane*3+1] = kp[1]; kb[lane*3+2] = kp[2];
    }
    float sA0 = 0.f, sA1 = 0.f, sB0 = 0.f, sB1 = 0.f;
    const float inv_s3 = 0.05103103630798287f;  // 1/sqrt(384)

    for (int r = 0; r < 25; r++) {
        int lr = w*25 + r;
        int buf = r & 1;

        uint32 kn0=0, kn1=0, kn2=0;
        if (r < 24) {
            int u = userL[lr + 1];
            const uint32* kp = (const uint32*)(KE + (size_t)u*C3) + lane*3;
            kn0 = kp[0]; kn1 = kp[1]; kn2 = kp[2];
        }

        if (lane < 50) {
            const unsigned short* kr = rowK[w*2 + buf];
            int base = 8400 - 84*lr;
            int d0a = (lane + base) % 100;
            int d0b = (lane + 50 + base) % 100;
            int qa = (lr*384 + d0a) / 100;
            int qb = (lr*384 + d0b) / 100;
            float ka0 = b2f(kr[d0a]), ka1 = b2f(kr[d0a+100]), ka2 = b2f(kr[d0a+200]);
            float kb0 = b2f(kr[d0b]), kb1 = b2f(kr[d0b+100]), kb2 = b2f(kr[d0b+200]);
            sA0 += qpA[qa]*ka0 + qpA[qa+1]*ka1 + qpA[qa+2]*ka2;
            sB0 += qpB[qa]*ka0 + qpB[qa+1]*ka1 + qpB[qa+2]*ka2;
            sA1 += qpA[qb]*kb0 + qpA[qb+1]*kb1 + qpA[qb+2]*kb2;
            sB1 += qpB[qb]*kb0 + qpB[qb+1]*kb1 + qpB[qb+2]*kb2;
            if (d0a < 84) {
                float k3 = b2f(kr[d0a+300]);
                sA0 += qpA[qa+3]*k3; sB0 += qpB[qa+3]*k3;
            }
            if (d0b < 84) {
                float k3 = b2f(kr[d0b+300]);
                sA1 += qpA[qb+3]*k3; sB1 += qpB[qb+3]*k3;
            }
        }

        if (r < 24) {
            uint32* kb = (uint32*)rowK[w*2 + (buf ^ 1)];
            kb[lane*3] = kn0; kb[lane*3+1] = kn1; kb[lane*3+2] = kn2;
        }
    }
    if (lane < 50) {
        sred[w][0][lane]      = sA0;
        sred[w][0][lane + 50] = sA1;
        sred[w][1][lane]      = sB0;
        sred[w][1][lane + 50] = sB1;
    }
    __syncthreads();

    // ---- e + den: wave0 -> pos, wave1 -> neg ----
    if (w < 2) {
        float den = 0.f;
        #pragma unroll
        for (int t = 0; t < 2; t++) {
            int bin = lane + t*64;
            if (bin < HIST) {
                float s = sred[0][w][bin] + sred[1][w][bin] + sred[2][w][bin] + sred[3][w][bin];
                float e = __expf(s * inv_s3);
                if (w == 0 && userL[bin] == ii) e = 0.f;
                eL[w][bin] = e;
                den += e;
            }
        }
        #pragma unroll
        for (int d = 1; d < 64; d <<= 1) den += __shfl_xor(den, d);
        if (lane == 0) scal[w] = sqrtf(den);   // den^BETA, and Sum(w) = den^(1-BETA)
    }
    __syncthreads();

    // ---- pass 2: preds, per-lane accumulation (no per-row reductions) ----
    float accP = 0.f, accN = 0.f;
    uint32 hc0, hc1, hc2;
    {
        int u = userL[w*25];
        const uint32* hp = (const uint32*)(Hsrc + (size_t)u*C3) + lane*3;
        hc0 = hp[0]; hc1 = hp[1]; hc2 = hp[2];
    }
    for (int r = 0; r < 25; r++) {
        int lr = w*25 + r;
        uint32 hn0=0, hn1=0, hn2=0;
        if (r < 24) {
            int u = userL[lr + 1];
            const uint32* hp = (const uint32*)(Hsrc + (size_t)u*C3) + lane*3;
            hn0 = hp[0]; hn1 = hp[1]; hn2 = hp[2];
        }
        float eA = eL[0][lr], eB = eL[1][lr];
        float lo0 = b2f(hc0 & 0xffff), hi0 = b2f(hc0 >> 16);
        float lo1 = b2f(hc1 & 0xffff), hi1 = b2f(hc1 >> 16);
        float lo2 = b2f(hc2 & 0xffff), hi2 = b2f(hc2 >> 16);
        float dp = lo0*gvp[0] + hi0*gvp[1] + lo1*gvp[2] + hi1*gvp[3] + lo2*gvp[4] + hi2*gvp[5];
        float dn = lo0*gvn[0] + hi0*gvn[1] + lo1*gvn[2] + hi1*gvn[3] + lo2*gvn[4] + hi2*gvn[5];
        accP += eA * dp;
        accN += eB * dn;
        hc0 = hn0; hc1 = hn1; hc2 = hn2;
    }
    #pragma unroll
    for (int d = 1; d < 64; d <<= 1) {
        accP += __shfl_xor(accP, d);
        accN += __shfl_xor(accN, d);
    }
    if (lane == 0) { red[w][0] = accP; red[w][1] = accN; }
    __syncthreads();
    if (tid == 0) {
        float np = red[0][0] + red[1][0] + red[2][0] + red[3][0];
        float nn = red[0][1] + red[1][1] + red[2][1] + red[3][1];
        out[b]         = np/scal[0] + scal[0]*cvv[0];
        out[BATCH + b] = nn/scal[1] + scal[1]*cvv[1];
    }
}

extern "C" void kernel_launch(void* const* d_in, const int* in_sizes, int n_in,
                              void* d_out, int out_size, void* d_ws, size_t ws_size,
                              hipStream_t stream)
{
    const int*   user     = (const int*)d_in[0];
    const int*   item_i   = (const int*)d_in[1];
    const int*   item_j   = (const int*)d_in[2];
    const float* emb_item = (const float*)d_in[3];
    const float* emb_in   = (const float*)d_in[4];
    const float* emb_out  = (const float*)d_in[5];
    const float* Wq = (const float*)d_in[6];
    const float* bq = (const float*)d_in[7];
    const float* Wk = (const float*)d_in[8];
    const float* bk = (const float*)d_in[9];
    const float* Wv = (const float*)d_in[10];
    const float* bv = (const float*)d_in[11];
    float* out = (float*)d_out;

    char* ws = (char*)d_ws;
    size_t off = 0;
    auto alloc = [&](size_t bytes) -> char* {
        char* p = ws + off;
        off = (off + bytes + 255) & ~(size_t)255;
        return p;
    };

    unsigned short* Qbf    = (unsigned short*)alloc((size_t)NPAD*C2*2);
    unsigned short* Hsrc   = (unsigned short*)alloc((size_t)N_IT*C3*2);
    unsigned short* WqB    = (unsigned short*)alloc((size_t)C3*C3*2);
    unsigned short* WkB    = (unsigned short*)alloc((size_t)C3*C3*2);
    unsigned short* WvTB   = (unsigned short*)alloc((size_t)C3*C3*2);
    unsigned short* KE     = (unsigned short*)alloc((size_t)N_IT*C3*2);
    float* QT              = (float*)alloc((size_t)2*BATCH*C3*4);
    float* GT              = (float*)alloc((size_t)2*BATCH*C3*4);
    float* Gpart           = (float*)alloc((size_t)NS*NTRI*4096*4);
    float* qsp             = (float*)alloc((size_t)NS*C2*4);
    unsigned short* GTswB  = (unsigned short*)alloc((size_t)C2*C2*2);
    float* qsumF           = (float*)alloc((size_t)C2*4);
    (void)ws_size;

    // 1) fused: gpart (500 blocks) + prep (2097 blocks)
    fusedA_kernel<<<NTRI*NS + 2097, 256, 0, stream>>>(emb_in, emb_out, emb_item,
                                                      Wq, Wk, Wv, Qbf, WqB, WkB, WvTB, Hsrc,
                                                      Gpart, qsp);
    // 2) combine -> GTswB bf16, qsumF
    gcomb_kernel<<<257, 256, 0, stream>>>(Gpart, qsp, GTswB, qsumF);
    // 3) region (+D) -> Hsrc[:,128:384] AND KE (fused), 32-row tiles
    gemmyKE_kernel<<<313, 256, 0, stream>>>(Qbf, GTswB, qsumF, WkB, bk, Hsrc, KE);
    // 4) QT/GT for gathered targets
    tgtQG_kernel<<<128, 256, 0, stream>>>(Hsrc, WqB, WvTB, bq, item_i, item_j, QT, GT);
    // 5) per-batch two-pass kernel
    batchD_kernel<<<BATCH, 256, 0, stream>>>(user, item_i, item_j, KE, QT, GT, bv, Hsrc, out);
}